// Round 6
// baseline (871.244 us; speedup 1.0000x reference)
//
#include <hip/hip_runtime.h>
#include <hip/hip_bf16.h>

#define N 4096
#define DMODEL 128
#define H 4
#define DK 32
#define NSPLIT 8
#define REP 32
// q is pre-scaled by (1/sqrt(32)) * log2(e) so all exponentials are raw v_exp_f32 (2^x)
#define QSCALE ((float)(0.17677669529663687 * 1.4426950408889634))

#if __has_builtin(__builtin_amdgcn_exp2f)
#define EXP2(x) __builtin_amdgcn_exp2f(x)
#else
#define EXP2(x) exp2f(x)
#endif

typedef __bf16 bf16x8 __attribute__((ext_vector_type(8)));
typedef __bf16 bf16x4 __attribute__((ext_vector_type(4)));
typedef float f32x4 __attribute__((ext_vector_type(4)));

// ---------------- projections (rep-instrumented) ----------------
__global__ __launch_bounds__(256, 4)
void proj_kernel(const float* __restrict__ x,
                 const float* __restrict__ Qw, const float* __restrict__ Qbias,
                 const float* __restrict__ Kw, const float* __restrict__ Kbias,
                 __bf16* __restrict__ qb, __bf16* __restrict__ kb, __bf16* __restrict__ xb,
                 int rep) {
  __shared__ __align__(16) float xs[128 * 16];  // [d][16 n]
  const int tid = threadIdx.x;
  const int n0 = blockIdx.x * 16;
  #pragma unroll
  for (int it = 0; it < 2; ++it) {
    int idx = tid + it * 256;        // f32x4 index, 512 total
    int dd = idx >> 2, j4 = idx & 3;
    f32x4 v = *(const f32x4*)(x + (size_t)dd * N + n0 + j4 * 4);
    ((f32x4*)xs)[idx] = v;
    bf16x4 o;
    o[0] = (__bf16)v[0]; o[1] = (__bf16)v[1]; o[2] = (__bf16)v[2]; o[3] = (__bf16)v[3];
    *(bf16x4*)(xb + (size_t)dd * N + n0 + j4 * 4) = o;
  }
  __syncthreads();
  const int a = tid & 127;   // output feature 0..127
  const int g = tid >> 7;    // 0 = q, 1 = k
  const float* __restrict__ W = g ? Kw : Qw;
  float acc[16];
  const f32x4* xs4 = (const f32x4*)xs;
  for (int r = 0; r < rep; ++r) {
    #pragma unroll
    for (int j = 0; j < 16; ++j) acc[j] = 0.f;
    #pragma unroll 8
    for (int dd = 0; dd < 128; ++dd) {
      float w = W[dd * 128 + a];
      #pragma unroll
      for (int jj = 0; jj < 4; ++jj) {
        f32x4 xv = xs4[dd * 4 + jj];
        #pragma unroll
        for (int e = 0; e < 4; ++e) acc[jj * 4 + e] += xv[e] * w;
      }
    }
    asm volatile("" : "+v"(acc[0]), "+v"(acc[1]), "+v"(acc[2]), "+v"(acc[3]),
                      "+v"(acc[4]), "+v"(acc[5]), "+v"(acc[6]), "+v"(acc[7]),
                      "+v"(acc[8]), "+v"(acc[9]), "+v"(acc[10]), "+v"(acc[11]),
                      "+v"(acc[12]), "+v"(acc[13]), "+v"(acc[14]), "+v"(acc[15]) :: "memory");
  }
  const float bias = (g ? Kbias : Qbias)[a];
  const float sc = g ? 1.0f : QSCALE;
  __bf16* __restrict__ dst = g ? kb : qb;
  const int h = a >> 5, c = a & 31;
  #pragma unroll
  for (int j = 0; j < 16; ++j)
    dst[((size_t)h * N + n0 + j) * DK + c] = (__bf16)((acc[j] + bias) * sc);
}

// ---------------- pass 1: Zinv (rep-instrumented) ----------------
__global__ __launch_bounds__(512, 4)
void z_kernel(const __bf16* __restrict__ qb, const __bf16* __restrict__ kb,
              float* __restrict__ Zinv, int rep) {
  const int h = blockIdx.x >> 6;
  const int n0 = (blockIdx.x & 63) * 64;
  const int wave = threadIdx.x >> 6;
  const int l = threadIdx.x & 63;
  const int lr = l & 15;
  const int kc = (l >> 4) * 8;
  bf16x8 qf[4];
  #pragma unroll
  for (int t = 0; t < 4; ++t)
    qf[t] = *(const bf16x8*)(qb + ((size_t)h * N + n0 + t * 16 + lr) * DK + kc);
  float z[16];
  const int mstart = wave * (N / 8);
  for (int r = 0; r < rep; ++r) {
    #pragma unroll
    for (int i = 0; i < 16; ++i) z[i] = 0.f;
    #pragma unroll 4
    for (int m0 = mstart; m0 < mstart + N / 8; m0 += 16) {
      bf16x8 kf = *(const bf16x8*)(kb + ((size_t)h * N + m0 + lr) * DK + kc);
      #pragma unroll
      for (int t = 0; t < 4; ++t) {
        f32x4 s = __builtin_amdgcn_mfma_f32_16x16x32_bf16(qf[t], kf, (f32x4){0.f, 0.f, 0.f, 0.f}, 0, 0, 0);
        #pragma unroll
        for (int j = 0; j < 4; ++j) z[t * 4 + j] += EXP2(s[j]);
      }
    }
    asm volatile("" : "+v"(z[0]), "+v"(z[1]), "+v"(z[2]), "+v"(z[3]),
                      "+v"(z[4]), "+v"(z[5]), "+v"(z[6]), "+v"(z[7]),
                      "+v"(z[8]), "+v"(z[9]), "+v"(z[10]), "+v"(z[11]),
                      "+v"(z[12]), "+v"(z[13]), "+v"(z[14]), "+v"(z[15]) :: "memory");
  }
  #pragma unroll
  for (int off = 1; off < 16; off <<= 1)
    #pragma unroll
    for (int i = 0; i < 16; ++i) z[i] += __shfl_xor(z[i], off, 64);
  __shared__ float zred[8][64];
  if (lr == 0) {
    int g = l >> 4;
    #pragma unroll
    for (int t = 0; t < 4; ++t)
      #pragma unroll
      for (int j = 0; j < 4; ++j) zred[wave][t * 16 + g * 4 + j] = z[t * 4 + j];
  }
  __syncthreads();
  if (threadIdx.x < 64) {
    int row = threadIdx.x;
    float s = 0.f;
    #pragma unroll
    for (int w = 0; w < 8; ++w) s += zred[w][row];
    Zinv[(size_t)h * N + n0 + row] = 1.0f / s;
  }
}

// ---------------- pass 2 (rep-instrumented) ----------------
__global__ __launch_bounds__(256, 3)
void attn_out_kernel(const __bf16* __restrict__ qb, const __bf16* __restrict__ kb,
                     const __bf16* __restrict__ xb, const float* __restrict__ Zinv,
                     float* __restrict__ partial, int rep) {
  const int mt = blockIdx.x & 63;
  const int sp = blockIdx.x >> 6;
  const int m0 = mt * 64;
  const int nstart = sp * (N / NSPLIT);
  const int nend = nstart + N / NSPLIT;
  const int wid = threadIdx.x >> 6;
  const int l = threadIdx.x & 63;
  const int lr = l & 15;
  const int lg = l >> 4;
  const int kc = lg * 8;

  __shared__ __align__(16) __bf16 PT[64][72];
  __shared__ float zl[H][64];

  bf16x8 kf[H][4];
  #pragma unroll
  for (int h = 0; h < H; ++h)
    #pragma unroll
    for (int t = 0; t < 4; ++t)
      kf[h][t] = *(const bf16x8*)(kb + ((size_t)h * N + m0 + t * 16 + lr) * DK + kc);

  f32x4 acc[2][4];

  // prologue prefetch (iteration 0); the n1 wrap below restores these for each rep
  float zv = Zinv[(size_t)wid * N + nstart + l];
  bf16x8 qf[H];
  #pragma unroll
  for (int h = 0; h < H; ++h)
    qf[h] = *(const bf16x8*)(qb + ((size_t)h * N + nstart + wid * 16 + lr) * DK + kc);

  for (int r = 0; r < rep; ++r) {
    #pragma unroll
    for (int dt = 0; dt < 2; ++dt)
      #pragma unroll
      for (int t = 0; t < 4; ++t) acc[dt][t] = (f32x4){0.f, 0.f, 0.f, 0.f};

    for (int n0 = nstart; n0 < nend; n0 += 64) {
      zl[wid][l] = zv;               // zl readers of prev iter finished before prev sync2
      __syncthreads();               // sync1: zl visible; PT free (prev PV readers done)

      const int n1 = (n0 + 64 < nend) ? n0 + 64 : nstart;
      float zv_n = Zinv[(size_t)wid * N + n1 + l];
      bf16x8 qf_n[H];
      #pragma unroll
      for (int h = 0; h < H; ++h)
        qf_n[h] = *(const bf16x8*)(qb + ((size_t)h * N + n1 + wid * 16 + lr) * DK + kc);

      float psum[4][4];
      #pragma unroll
      for (int t = 0; t < 4; ++t)
        #pragma unroll
        for (int j = 0; j < 4; ++j) psum[t][j] = 0.f;

      #pragma unroll
      for (int h = 0; h < H; ++h) {
        float zi[4];
        #pragma unroll
        for (int j = 0; j < 4; ++j) zi[j] = zl[h][wid * 16 + lg * 4 + j];
        #pragma unroll
        for (int t = 0; t < 4; ++t) {
          f32x4 s = __builtin_amdgcn_mfma_f32_16x16x32_bf16(qf[h], kf[h][t],
                                                            (f32x4){0.f, 0.f, 0.f, 0.f}, 0, 0, 0);
          #pragma unroll
          for (int j = 0; j < 4; ++j)
            psum[t][j] += EXP2(s[j]) * zi[j];
        }
      }
      #pragma unroll
      for (int t = 0; t < 4; ++t) {
        bf16x4 pw;
        #pragma unroll
        for (int j = 0; j < 4; ++j) pw[j] = (__bf16)(psum[t][j] * 0.25f);
        *(bf16x4*)(&PT[t * 16 + lr][wid * 16 + lg * 4]) = pw;
      }

      bf16x8 xa[2][2];
      #pragma unroll
      for (int kb2 = 0; kb2 < 2; ++kb2)
        #pragma unroll
        for (int dt = 0; dt < 2; ++dt)
          xa[kb2][dt] = *(const bf16x8*)(xb + (size_t)(wid * 32 + dt * 16 + lr) * N + n0 + kb2 * 32 + kc);
      __syncthreads();               // sync2: PT visible to PV readers

      #pragma unroll
      for (int kb2 = 0; kb2 < 2; ++kb2) {
        #pragma unroll
        for (int t = 0; t < 4; ++t) {
          bf16x8 pf = *(const bf16x8*)(&PT[t * 16 + lr][kb2 * 32 + kc]);
          #pragma unroll
          for (int dt = 0; dt < 2; ++dt)
            acc[dt][t] = __builtin_amdgcn_mfma_f32_16x16x32_bf16(xa[kb2][dt], pf, acc[dt][t], 0, 0, 0);
        }
      }
      zv = zv_n;
      #pragma unroll
      for (int h = 0; h < H; ++h) qf[h] = qf_n[h];
    }
    asm volatile("" : "+v"(acc[0][0]), "+v"(acc[0][1]), "+v"(acc[0][2]), "+v"(acc[0][3]),
                      "+v"(acc[1][0]), "+v"(acc[1][1]), "+v"(acc[1][2]), "+v"(acc[1][3]) :: "memory");
  }

  #pragma unroll
  for (int dt = 0; dt < 2; ++dt)
    #pragma unroll
    for (int t = 0; t < 4; ++t)
      #pragma unroll
      for (int j = 0; j < 4; ++j)
        partial[((size_t)sp * DMODEL + wid * 32 + dt * 16 + lg * 4 + j) * N + m0 + t * 16 + lr] =
            acc[dt][t][j];
}

// ---------------- reduce (rep-instrumented) ----------------
__global__ void reduce_kernel(const float* __restrict__ partial, float* __restrict__ out, int rep) {
  int i = blockIdx.x * 256 + threadIdx.x;
  const f32x4* p = (const f32x4*)partial;
  f32x4 s;
  for (int r = 0; r < rep; ++r) {
    s = p[i];
    #pragma unroll
    for (int sp = 1; sp < NSPLIT; ++sp) s += p[(size_t)sp * (DMODEL * N / 4) + i];
    asm volatile("" : "+v"(s) :: "memory");
  }
  ((f32x4*)out)[i] = s;
}

extern "C" void kernel_launch(void* const* d_in, const int* in_sizes, int n_in,
                              void* d_out, int out_size, void* d_ws, size_t ws_size,
                              hipStream_t stream) {
  (void)in_sizes; (void)n_in; (void)out_size; (void)ws_size;
  const float* x  = (const float*)d_in[0];
  const float* Qw = (const float*)d_in[1];
  const float* Qb = (const float*)d_in[2];
  const float* Kw = (const float*)d_in[3];
  const float* Kb = (const float*)d_in[4];

  char* ws = (char*)d_ws;
  __bf16* qb   = (__bf16*)(ws);                          // 1 MB
  __bf16* kb   = (__bf16*)(ws + (1 << 20));              // 1 MB
  __bf16* xb   = (__bf16*)(ws + (2 << 20));              // 1 MB
  float*  Zinv = (float*)(ws + (3 << 20));               // 64 KB
  float*  part = (float*)(ws + (3 << 20) + (1 << 16));   // 16 MB
  float*  out  = (float*)d_out;

  proj_kernel<<<dim3(N / 16), dim3(256), 0, stream>>>(x, Qw, Qb, Kw, Kb, qb, kb, xb, REP);
  z_kernel<<<dim3(H * (N / 64)), dim3(512), 0, stream>>>(qb, kb, Zinv, REP);
  attn_out_kernel<<<dim3(64 * NSPLIT), dim3(256), 0, stream>>>(qb, kb, xb, Zinv, part, REP);
  reduce_kernel<<<dim3(DMODEL * N / (4 * 256)), dim3(256), 0, stream>>>(part, out, REP);
}

// Round 7
// 59.892 us; speedup vs baseline: 14.5470x; 14.5470x over previous
//
#include <hip/hip_runtime.h>
#include <hip/hip_bf16.h>

#define N 4096
#define DMODEL 128
#define H 4
#define DK 32
#define NSPLIT 8
// q is pre-scaled by (1/sqrt(32)) * log2(e) so all exponentials are raw v_exp_f32 (2^x)
#define QSCALE ((float)(0.17677669529663687 * 1.4426950408889634))

#if __has_builtin(__builtin_amdgcn_exp2f)
#define EXP2(x) __builtin_amdgcn_exp2f(x)
#else
#define EXP2(x) exp2f(x)
#endif

typedef __bf16 bf16x8 __attribute__((ext_vector_type(8)));
typedef __bf16 bf16x4 __attribute__((ext_vector_type(4)));
typedef float f32x4 __attribute__((ext_vector_type(4)));

// ---------------- projections: q~ = (x^T Qw + Qb)*QSCALE, k = x^T Kw + Kb; also x -> bf16 ----
// grid 512 blocks x 256 threads; block owns 8 n-columns (2 blocks/CU).
__global__ __launch_bounds__(256, 4)
void proj_kernel(const float* __restrict__ x,
                 const float* __restrict__ Qw, const float* __restrict__ Qbias,
                 const float* __restrict__ Kw, const float* __restrict__ Kbias,
                 __bf16* __restrict__ qb, __bf16* __restrict__ kb, __bf16* __restrict__ xb) {
  __shared__ __align__(16) float xs[128 * 8];  // [d][8 n]
  const int tid = threadIdx.x;
  const int n0 = blockIdx.x * 8;
  {
    int dd = tid >> 1, j4 = tid & 1;           // 256 f32x4 = whole tile
    f32x4 v = *(const f32x4*)(x + (size_t)dd * N + n0 + j4 * 4);
    ((f32x4*)xs)[tid] = v;
    bf16x4 o;
    o[0] = (__bf16)v[0]; o[1] = (__bf16)v[1]; o[2] = (__bf16)v[2]; o[3] = (__bf16)v[3];
    *(bf16x4*)(xb + (size_t)dd * N + n0 + j4 * 4) = o;
  }
  __syncthreads();
  const int a = tid & 127;   // output feature 0..127
  const int g = tid >> 7;    // 0 = q, 1 = k
  const float* __restrict__ W = g ? Kw : Qw;
  float acc[8];
  #pragma unroll
  for (int j = 0; j < 8; ++j) acc[j] = 0.f;
  const f32x4* xs4 = (const f32x4*)xs;
  #pragma unroll 8
  for (int dd = 0; dd < 128; ++dd) {
    float w = W[dd * 128 + a];
    #pragma unroll
    for (int jj = 0; jj < 2; ++jj) {
      f32x4 xv = xs4[dd * 2 + jj];
      #pragma unroll
      for (int e = 0; e < 4; ++e) acc[jj * 4 + e] += xv[e] * w;
    }
  }
  const float bias = (g ? Kbias : Qbias)[a];
  const float sc = g ? 1.0f : QSCALE;
  __bf16* __restrict__ dst = g ? kb : qb;
  const int h = a >> 5, c = a & 31;
  #pragma unroll
  for (int j = 0; j < 8; ++j)
    dst[((size_t)h * N + n0 + j) * DK + c] = (__bf16)((acc[j] + bias) * sc);
}

// ---------------- pass 1: Zinv[h][n] = 1 / sum_m exp2(q~_n . k_m) ----------------
// grid: H * N/64 = 256 blocks x 1024 threads (16 waves/CU, 50% occ). Block owns 64 n rows
// (4 q-fragments per wave, k-fragment reused 4x); waves split the m range 16 ways.
__global__ __launch_bounds__(1024, 4)
void z_kernel(const __bf16* __restrict__ qb, const __bf16* __restrict__ kb,
              float* __restrict__ Zinv) {
  const int h = blockIdx.x >> 6;
  const int n0 = (blockIdx.x & 63) * 64;
  const int wave = threadIdx.x >> 6;
  const int l = threadIdx.x & 63;
  const int lr = l & 15;
  const int kc = (l >> 4) * 8;
  bf16x8 qf[4];
  #pragma unroll
  for (int t = 0; t < 4; ++t)
    qf[t] = *(const bf16x8*)(qb + ((size_t)h * N + n0 + t * 16 + lr) * DK + kc);
  float z[16];
  #pragma unroll
  for (int i = 0; i < 16; ++i) z[i] = 0.f;
  const int mstart = wave * (N / 16);
  #pragma unroll 2
  for (int m0 = mstart; m0 < mstart + N / 16; m0 += 16) {
    bf16x8 kf = *(const bf16x8*)(kb + ((size_t)h * N + m0 + lr) * DK + kc);
    #pragma unroll
    for (int t = 0; t < 4; ++t) {
      f32x4 s = __builtin_amdgcn_mfma_f32_16x16x32_bf16(qf[t], kf, (f32x4){0.f, 0.f, 0.f, 0.f}, 0, 0, 0);
      #pragma unroll
      for (int j = 0; j < 4; ++j) z[t * 4 + j] += EXP2(s[j]);
    }
  }
  #pragma unroll
  for (int off = 1; off < 16; off <<= 1)
    #pragma unroll
    for (int i = 0; i < 16; ++i) z[i] += __shfl_xor(z[i], off, 64);
  __shared__ float zred[16][64];
  if (lr == 0) {
    int g = l >> 4;
    #pragma unroll
    for (int t = 0; t < 4; ++t)
      #pragma unroll
      for (int j = 0; j < 4; ++j) zred[wave][t * 16 + g * 4 + j] = z[t * 4 + j];
  }
  __syncthreads();
  if (threadIdx.x < 64) {
    int row = threadIdx.x;
    float s = 0.f;
    #pragma unroll
    for (int w = 0; w < 16; ++w) s += zred[w][row];
    Zinv[(size_t)h * N + n0 + row] = 1.0f / s;
  }
}

// ---------------- pass 2: out partial = x @ P_mean for a 32-col m tile, 1/NSPLIT of n ----
// grid 1024 blocks (128 m-tiles x 8 n-splits) x 256 threads -> 4 blocks/CU, 16 waves/CU.
// Zinv read directly from global (L1-resident) as f32x4 per lane -- no zl LDS.
// Per iter: S compute (no LDS) -> sync1 -> PT write -> xa loads -> sync2 -> PV.
__global__ __launch_bounds__(256, 4)
void attn_out_kernel(const __bf16* __restrict__ qb, const __bf16* __restrict__ kb,
                     const __bf16* __restrict__ xb, const float* __restrict__ Zinv,
                     float* __restrict__ partial) {
  const int mt = blockIdx.x & 127;
  const int sp = blockIdx.x >> 7;
  const int m0 = mt * 32;
  const int nstart = sp * (N / NSPLIT);
  const int nend = nstart + N / NSPLIT;
  const int wid = threadIdx.x >> 6;
  const int l = threadIdx.x & 63;
  const int lr = l & 15;
  const int lg = l >> 4;
  const int kc = lg * 8;

  __shared__ __align__(16) __bf16 PT[32][72];  // [m][n], +8 pad

  bf16x8 kf[H][2];
  #pragma unroll
  for (int h = 0; h < H; ++h)
    #pragma unroll
    for (int t = 0; t < 2; ++t)
      kf[h][t] = *(const bf16x8*)(kb + ((size_t)h * N + m0 + t * 16 + lr) * DK + kc);

  f32x4 acc[2][2];
  #pragma unroll
  for (int dt = 0; dt < 2; ++dt)
    #pragma unroll
    for (int t = 0; t < 2; ++t) acc[dt][t] = (f32x4){0.f, 0.f, 0.f, 0.f};

  for (int n0 = nstart; n0 < nend; n0 += 64) {
    // ---- S phase: this wave's 16 n rows, all 4 heads summed in registers (no LDS) ----
    float psum[2][4];
    #pragma unroll
    for (int t = 0; t < 2; ++t)
      #pragma unroll
      for (int j = 0; j < 4; ++j) psum[t][j] = 0.f;

    #pragma unroll
    for (int h = 0; h < H; ++h) {
      bf16x8 qf = *(const bf16x8*)(qb + ((size_t)h * N + n0 + wid * 16 + lr) * DK + kc);
      f32x4 zi = *(const f32x4*)(Zinv + (size_t)h * N + n0 + wid * 16 + lg * 4);
      #pragma unroll
      for (int t = 0; t < 2; ++t) {
        f32x4 s = __builtin_amdgcn_mfma_f32_16x16x32_bf16(qf, kf[h][t],
                                                          (f32x4){0.f, 0.f, 0.f, 0.f}, 0, 0, 0);
        #pragma unroll
        for (int j = 0; j < 4; ++j)
          psum[t][j] += EXP2(s[j]) * zi[j];
      }
    }
    __syncthreads();               // sync1: prev iter's PV readers done -> PT writable

    #pragma unroll
    for (int t = 0; t < 2; ++t) {
      bf16x4 pw;
      #pragma unroll
      for (int j = 0; j < 4; ++j) pw[j] = (__bf16)(psum[t][j] * 0.25f);
      *(bf16x4*)(&PT[t * 16 + lr][wid * 16 + lg * 4]) = pw;
    }

    // xa loads don't touch LDS: issue before the barrier to overlap it
    bf16x8 xa[2][2];
    #pragma unroll
    for (int kb2 = 0; kb2 < 2; ++kb2)
      #pragma unroll
      for (int dt = 0; dt < 2; ++dt)
        xa[kb2][dt] = *(const bf16x8*)(xb + (size_t)(wid * 32 + dt * 16 + lr) * N + n0 + kb2 * 32 + kc);
    __syncthreads();               // sync2: PT visible to PV readers

    // ---- PV phase ----
    #pragma unroll
    for (int kb2 = 0; kb2 < 2; ++kb2) {
      #pragma unroll
      for (int t = 0; t < 2; ++t) {
        bf16x8 pf = *(const bf16x8*)(&PT[t * 16 + lr][kb2 * 32 + kc]);
        #pragma unroll
        for (int dt = 0; dt < 2; ++dt)
          acc[dt][t] = __builtin_amdgcn_mfma_f32_16x16x32_bf16(xa[kb2][dt], pf, acc[dt][t], 0, 0, 0);
      }
    }
  }

  #pragma unroll
  for (int dt = 0; dt < 2; ++dt)
    #pragma unroll
    for (int t = 0; t < 2; ++t)
      #pragma unroll
      for (int j = 0; j < 4; ++j)
        partial[((size_t)sp * DMODEL + wid * 32 + dt * 16 + lg * 4 + j) * N + m0 + t * 16 + lr] =
            acc[dt][t][j];
}

// ---------------- reduce the NSPLIT partials ----------------
__global__ void reduce_kernel(const float* __restrict__ partial, float* __restrict__ out) {
  int i = blockIdx.x * 256 + threadIdx.x;
  const f32x4* p = (const f32x4*)partial;
  f32x4 s = p[i];
  #pragma unroll
  for (int sp = 1; sp < NSPLIT; ++sp) s += p[(size_t)sp * (DMODEL * N / 4) + i];
  ((f32x4*)out)[i] = s;
}

extern "C" void kernel_launch(void* const* d_in, const int* in_sizes, int n_in,
                              void* d_out, int out_size, void* d_ws, size_t ws_size,
                              hipStream_t stream) {
  (void)in_sizes; (void)n_in; (void)out_size; (void)ws_size;
  const float* x  = (const float*)d_in[0];
  const float* Qw = (const float*)d_in[1];
  const float* Qb = (const float*)d_in[2];
  const float* Kw = (const float*)d_in[3];
  const float* Kb = (const float*)d_in[4];

  char* ws = (char*)d_ws;
  __bf16* qb   = (__bf16*)(ws);                          // 1 MB
  __bf16* kb   = (__bf16*)(ws + (1 << 20));              // 1 MB
  __bf16* xb   = (__bf16*)(ws + (2 << 20));              // 1 MB
  float*  Zinv = (float*)(ws + (3 << 20));               // 64 KB
  float*  part = (float*)(ws + (3 << 20) + (1 << 16));   // 16 MB
  float*  out  = (float*)d_out;

  proj_kernel<<<dim3(N / 8), dim3(256), 0, stream>>>(x, Qw, Qb, Kw, Kb, qb, kb, xb);
  z_kernel<<<dim3(H * (N / 64)), dim3(1024), 0, stream>>>(qb, kb, Zinv);
  attn_out_kernel<<<dim3(128 * NSPLIT), dim3(256), 0, stream>>>(qb, kb, xb, Zinv, part);
  reduce_kernel<<<dim3(DMODEL * N / (4 * 256)), dim3(256), 0, stream>>>(part, out);
}

// Round 8
// 56.886 us; speedup vs baseline: 15.3156x; 1.0528x over previous
//
#include <hip/hip_runtime.h>
#include <hip/hip_bf16.h>

#define N 4096
#define DMODEL 128
#define H 4
#define DK 32
#define NSPLIT 8
// q is pre-scaled by (1/sqrt(32)) * log2(e) so all exponentials are raw v_exp_f32 (2^x)
#define QSCALE ((float)(0.17677669529663687 * 1.4426950408889634))

#if __has_builtin(__builtin_amdgcn_exp2f)
#define EXP2(x) __builtin_amdgcn_exp2f(x)
#else
#define EXP2(x) exp2f(x)
#endif

typedef __bf16 bf16x8 __attribute__((ext_vector_type(8)));
typedef __bf16 bf16x4 __attribute__((ext_vector_type(4)));
typedef float f32x4 __attribute__((ext_vector_type(4)));

// ---------------- projections: q~ = (x^T Qw + Qb)*QSCALE, k = x^T Kw + Kb; also x -> bf16 ----
// grid 256 blocks x 256 threads; block owns 16 n-columns (R5-proven shape: weight re-read
// traffic 32 MB; more blocks doubles it for no win).
__global__ __launch_bounds__(256, 4)
void proj_kernel(const float* __restrict__ x,
                 const float* __restrict__ Qw, const float* __restrict__ Qbias,
                 const float* __restrict__ Kw, const float* __restrict__ Kbias,
                 __bf16* __restrict__ qb, __bf16* __restrict__ kb, __bf16* __restrict__ xb) {
  __shared__ __align__(16) float xs[128 * 16];  // [d][16 n]
  const int tid = threadIdx.x;
  const int n0 = blockIdx.x * 16;
  #pragma unroll
  for (int it = 0; it < 2; ++it) {
    int idx = tid + it * 256;        // f32x4 index, 512 total
    int dd = idx >> 2, j4 = idx & 3;
    f32x4 v = *(const f32x4*)(x + (size_t)dd * N + n0 + j4 * 4);
    ((f32x4*)xs)[idx] = v;
    bf16x4 o;
    o[0] = (__bf16)v[0]; o[1] = (__bf16)v[1]; o[2] = (__bf16)v[2]; o[3] = (__bf16)v[3];
    *(bf16x4*)(xb + (size_t)dd * N + n0 + j4 * 4) = o;
  }
  __syncthreads();
  const int a = tid & 127;   // output feature 0..127
  const int g = tid >> 7;    // 0 = q, 1 = k
  const float* __restrict__ W = g ? Kw : Qw;
  float acc[16];
  #pragma unroll
  for (int j = 0; j < 16; ++j) acc[j] = 0.f;
  const f32x4* xs4 = (const f32x4*)xs;
  #pragma unroll 8
  for (int dd = 0; dd < 128; ++dd) {
    float w = W[dd * 128 + a];
    #pragma unroll
    for (int jj = 0; jj < 4; ++jj) {
      f32x4 xv = xs4[dd * 4 + jj];
      #pragma unroll
      for (int e = 0; e < 4; ++e) acc[jj * 4 + e] += xv[e] * w;
    }
  }
  const float bias = (g ? Kbias : Qbias)[a];
  const float sc = g ? 1.0f : QSCALE;
  __bf16* __restrict__ dst = g ? kb : qb;
  const int h = a >> 5, c = a & 31;
  #pragma unroll
  for (int j = 0; j < 16; ++j)
    dst[((size_t)h * N + n0 + j) * DK + c] = (__bf16)((acc[j] + bias) * sc);
}

// ---------------- pass 1: Zinv[h][n] = 1 / sum_m exp2(q~_n . k_m) ----------------
// grid: H * N/64 = 256 blocks x 1024 threads (16 waves/CU). Block owns 64 n rows;
// waves split the m range 16 ways. Same k traffic as the 8-wave version, 2x waves.
__global__ __launch_bounds__(1024, 4)
void z_kernel(const __bf16* __restrict__ qb, const __bf16* __restrict__ kb,
              float* __restrict__ Zinv) {
  const int h = blockIdx.x >> 6;
  const int n0 = (blockIdx.x & 63) * 64;
  const int wave = threadIdx.x >> 6;
  const int l = threadIdx.x & 63;
  const int lr = l & 15;
  const int kc = (l >> 4) * 8;
  bf16x8 qf[4];
  #pragma unroll
  for (int t = 0; t < 4; ++t)
    qf[t] = *(const bf16x8*)(qb + ((size_t)h * N + n0 + t * 16 + lr) * DK + kc);
  float z[16];
  #pragma unroll
  for (int i = 0; i < 16; ++i) z[i] = 0.f;
  const int mstart = wave * (N / 16);
  #pragma unroll 2
  for (int m0 = mstart; m0 < mstart + N / 16; m0 += 16) {
    bf16x8 kf = *(const bf16x8*)(kb + ((size_t)h * N + m0 + lr) * DK + kc);
    #pragma unroll
    for (int t = 0; t < 4; ++t) {
      f32x4 s = __builtin_amdgcn_mfma_f32_16x16x32_bf16(qf[t], kf, (f32x4){0.f, 0.f, 0.f, 0.f}, 0, 0, 0);
      #pragma unroll
      for (int j = 0; j < 4; ++j) z[t * 4 + j] += EXP2(s[j]);
    }
  }
  #pragma unroll
  for (int off = 1; off < 16; off <<= 1)
    #pragma unroll
    for (int i = 0; i < 16; ++i) z[i] += __shfl_xor(z[i], off, 64);
  __shared__ float zred[16][64];
  if (lr == 0) {
    int g = l >> 4;
    #pragma unroll
    for (int t = 0; t < 4; ++t)
      #pragma unroll
      for (int j = 0; j < 4; ++j) zred[wave][t * 16 + g * 4 + j] = z[t * 4 + j];
  }
  __syncthreads();
  if (threadIdx.x < 64) {
    int row = threadIdx.x;
    float s = 0.f;
    #pragma unroll
    for (int w = 0; w < 16; ++w) s += zred[w][row];
    Zinv[(size_t)h * N + n0 + row] = 1.0f / s;
  }
}

// ---------------- pass 2: out partial = x @ P_mean for a 64-col m tile, 1/NSPLIT of n ----
// grid 512 blocks x 512 threads (8 waves) -> 2 blocks/CU, 16 waves/CU; SAME per-block
// data footprint as the R5 kernel (traffic unchanged), 2x resident waves.
// Wave w: S phase owns n-subtile (w&3) x m-half (w>>2); PV phase owns d-rows [16w,16w+16).
// Per iter: S compute (regs only) -> sync1 -> PT write + xa loads -> sync2 -> PV.
__global__ __launch_bounds__(512, 4)
void attn_out_kernel(const __bf16* __restrict__ qb, const __bf16* __restrict__ kb,
                     const __bf16* __restrict__ xb, const float* __restrict__ Zinv,
                     float* __restrict__ partial) {
  const int mt = blockIdx.x & 63;
  const int sp = blockIdx.x >> 6;
  const int m0 = mt * 64;
  const int nstart = sp * (N / NSPLIT);
  const int nend = nstart + N / NSPLIT;
  const int w = threadIdx.x >> 6;   // 0..7
  const int gn = w & 3;             // n-subtile in S phase
  const int gm = w >> 2;            // m-half in S phase
  const int l = threadIdx.x & 63;
  const int lr = l & 15;
  const int lg = l >> 4;
  const int kc = lg * 8;

  __shared__ __align__(16) __bf16 PT[64][72];  // [m][n], +8 pad

  bf16x8 kf[H][2];
  #pragma unroll
  for (int h = 0; h < H; ++h)
    #pragma unroll
    for (int t = 0; t < 2; ++t)
      kf[h][t] = *(const bf16x8*)(kb + ((size_t)h * N + m0 + gm * 32 + t * 16 + lr) * DK + kc);

  f32x4 acc[4];
  #pragma unroll
  for (int t = 0; t < 4; ++t) acc[t] = (f32x4){0.f, 0.f, 0.f, 0.f};

  // prologue prefetch (iteration 0)
  bf16x8 qf[H];
  #pragma unroll
  for (int h = 0; h < H; ++h)
    qf[h] = *(const bf16x8*)(qb + ((size_t)h * N + nstart + gn * 16 + lr) * DK + kc);

  for (int n0 = nstart; n0 < nend; n0 += 64) {
    // next-iteration prefetch overlaps the S-phase compute
    const int n1 = (n0 + 64 < nend) ? n0 + 64 : nstart;
    bf16x8 qf_n[H];
    #pragma unroll
    for (int h = 0; h < H; ++h)
      qf_n[h] = *(const bf16x8*)(qb + ((size_t)h * N + n1 + gn * 16 + lr) * DK + kc);

    // ---- S phase: n-rows [n0+gn*16), m-cols [m0+gm*32, +32), all 4 heads (regs only) ----
    float psum[2][4];
    #pragma unroll
    for (int t = 0; t < 2; ++t)
      #pragma unroll
      for (int j = 0; j < 4; ++j) psum[t][j] = 0.f;

    #pragma unroll
    for (int h = 0; h < H; ++h) {
      f32x4 zi = *(const f32x4*)(Zinv + (size_t)h * N + n0 + gn * 16 + lg * 4);
      #pragma unroll
      for (int t = 0; t < 2; ++t) {
        f32x4 s = __builtin_amdgcn_mfma_f32_16x16x32_bf16(qf[h], kf[h][t],
                                                          (f32x4){0.f, 0.f, 0.f, 0.f}, 0, 0, 0);
        #pragma unroll
        for (int j = 0; j < 4; ++j)
          psum[t][j] += EXP2(s[j]) * zi[j];
      }
    }
    bf16x4 pw[2];
    #pragma unroll
    for (int t = 0; t < 2; ++t)
      #pragma unroll
      for (int j = 0; j < 4; ++j) pw[t][j] = (__bf16)(psum[t][j] * 0.25f);

    __syncthreads();               // sync1: prev iter's PV readers done -> PT writable

    #pragma unroll
    for (int t = 0; t < 2; ++t)
      *(bf16x4*)(&PT[gm * 32 + t * 16 + lr][gn * 16 + lg * 4]) = pw[t];

    // xa loads don't touch LDS: issue before the barrier to overlap it
    bf16x8 xa[2];
    #pragma unroll
    for (int kb2 = 0; kb2 < 2; ++kb2)
      xa[kb2] = *(const bf16x8*)(xb + (size_t)(w * 16 + lr) * N + n0 + kb2 * 32 + kc);
    __syncthreads();               // sync2: PT visible to PV readers

    // ---- PV phase: acc[d-rows 16w..16w+16][m] += x_tile @ P_tile ----
    #pragma unroll
    for (int kb2 = 0; kb2 < 2; ++kb2) {
      #pragma unroll
      for (int t = 0; t < 4; ++t) {
        bf16x8 pf = *(const bf16x8*)(&PT[t * 16 + lr][kb2 * 32 + kc]);
        acc[t] = __builtin_amdgcn_mfma_f32_16x16x32_bf16(xa[kb2], pf, acc[t], 0, 0, 0);
      }
    }
    #pragma unroll
    for (int h = 0; h < H; ++h) qf[h] = qf_n[h];
  }

  #pragma unroll
  for (int t = 0; t < 4; ++t)
    #pragma unroll
    for (int j = 0; j < 4; ++j)
      partial[((size_t)sp * DMODEL + w * 16 + lg * 4 + j) * N + m0 + t * 16 + lr] = acc[t][j];
}

// ---------------- reduce the NSPLIT partials ----------------
__global__ void reduce_kernel(const float* __restrict__ partial, float* __restrict__ out) {
  int i = blockIdx.x * 256 + threadIdx.x;
  const f32x4* p = (const f32x4*)partial;
  f32x4 s = p[i];
  #pragma unroll
  for (int sp = 1; sp < NSPLIT; ++sp) s += p[(size_t)sp * (DMODEL * N / 4) + i];
  ((f32x4*)out)[i] = s;
}

extern "C" void kernel_launch(void* const* d_in, const int* in_sizes, int n_in,
                              void* d_out, int out_size, void* d_ws, size_t ws_size,
                              hipStream_t stream) {
  (void)in_sizes; (void)n_in; (void)out_size; (void)ws_size;
  const float* x  = (const float*)d_in[0];
  const float* Qw = (const float*)d_in[1];
  const float* Qb = (const float*)d_in[2];
  const float* Kw = (const float*)d_in[3];
  const float* Kb = (const float*)d_in[4];

  char* ws = (char*)d_ws;
  __bf16* qb   = (__bf16*)(ws);                          // 1 MB
  __bf16* kb   = (__bf16*)(ws + (1 << 20));              // 1 MB
  __bf16* xb   = (__bf16*)(ws + (2 << 20));              // 1 MB
  float*  Zinv = (float*)(ws + (3 << 20));               // 64 KB
  float*  part = (float*)(ws + (3 << 20) + (1 << 16));   // 16 MB
  float*  out  = (float*)d_out;

  proj_kernel<<<dim3(N / 16), dim3(256), 0, stream>>>(x, Qw, Qb, Kw, Kb, qb, kb, xb);
  z_kernel<<<dim3(H * (N / 64)), dim3(1024), 0, stream>>>(qb, kb, Zinv);
  attn_out_kernel<<<dim3(64 * NSPLIT), dim3(512), 0, stream>>>(qb, kb, xb, Zinv, part);
  reduce_kernel<<<dim3(DMODEL * N / (4 * 256)), dim3(256), 0, stream>>>(part, out);
}